// Round 8
// baseline (222.413 us; speedup 1.0000x reference)
//
#include <hip/hip_runtime.h>
#include <math.h>

#define A_N   8732
#define A_PAD 8736            // A_N rounded up to 8 (u16 pad, zeros)
#define C_N   81
#define B_N   32
#define NCLS  80
#define NTASK (B_N * NCLS)
#define TOPK  100
#define NTHR  256
#define CAND  512
#define TA    64
#define NV4K  (A_PAD / 8)     // 1092 uint4 (8 u16 keys each) per key row
#define KPT16 5               // ceil(NV4K / NTHR)
#define K0    0xBE00u         // k16 >= K0  <=>  x >= 0.125
#define NBIN  128             // fine bins of 16 u16-steps over [K0, K0+2048)

// ln(3/7) in f64: sigmoid_f64(x) > 0.3  <=>  x > THR_LOGIT
#define THR_LOGIT (-0.8472978603872034)

// Monotone map: float bits -> unsigned, order-preserving. 0 = invalid sentinel.
__device__ __forceinline__ unsigned mapf(float x) {
    unsigned b = __float_as_uint(x);
    return b ^ ((b & 0x80000000u) ? 0xFFFFFFFFu : 0x80000000u);
}
__device__ __forceinline__ float unmapf(unsigned u) {
    unsigned b = (u & 0x80000000u) ? (u ^ 0x80000000u) : ~u;
    return __uint_as_float(b);
}

// Exact f64 decode (reference op order) from raw regression/prior values.
__device__ __forceinline__ void dec64(const float4 r4, const float4 p4,
                                      double* bx, double* area) {
    double ty = (double)r4.x / 10.0, tx = (double)r4.y / 10.0;
    double th = (double)r4.z / 5.0,  tw = (double)r4.w / 5.0;
    double cy = ty * (double)p4.z + (double)p4.x;
    double cx = tx * (double)p4.w + (double)p4.y;
    double hh = exp(th) * (double)p4.z;
    double ww = exp(tw) * (double)p4.w;
    bx[0] = cy - hh / 2.0; bx[1] = cx - ww / 2.0;
    bx[2] = cy + hh / 2.0; bx[3] = cx + ww / 2.0;
    double e0 = bx[2] - bx[0]; if (e0 < 0.0) e0 = 0.0;
    double e1 = bx[3] - bx[1]; if (e1 < 0.0) e1 = 0.0;
    *area = e0 * e1;
}

// ---- Kernel T: coalesced logits read -> u16 keys (B,80,A_PAD) + per-task fine hist
__global__ __launch_bounds__(NTHR) void key_transpose_kernel(
    const float* __restrict__ logits,          // (B, A, 81)
    unsigned short* __restrict__ keys,         // (B, 80, A_PAD) u16
    unsigned* __restrict__ ghist)              // (NTASK, NBIN) u32, pre-zeroed
{
    __shared__ unsigned short tile[NCLS][TA + 2];      // 10.3 KB
    __shared__ unsigned hpack[NCLS * (NBIN / 4)];      // 80*32 u32, 4 u8 counters each
    const int NT = (A_N + TA - 1) / TA;                // 137
    const int b  = blockIdx.x / NT;
    const int t0 = blockIdx.x % NT;
    const int a0 = t0 * TA;
    const int an = min(TA, A_N - a0);
    const int tid = threadIdx.x;

    for (int i = tid; i < NCLS * (NBIN / 4); i += NTHR) hpack[i] = 0;
    __syncthreads();

    const float* src = logits + ((size_t)b * A_N + a0) * C_N;

    if (an == TA) {
        const float4* src4 = (const float4*)src;
        const int total4 = TA * C_N / 4;               // 1296
        for (int i = tid; i < total4; i += NTHR) {
            float4 v = src4[i];
            int base = 4 * i;
            int r  = base / C_N;
            int ch = base - r * C_N;
            float xs[4] = { v.x, v.y, v.z, v.w };
            #pragma unroll
            for (int k = 0; k < 4; ++k) {
                if (ch > 0) {
                    unsigned k16 = ((double)xs[k] > THR_LOGIT) ? (mapf(xs[k]) >> 16) : 0u;
                    tile[ch - 1][r] = (unsigned short)k16;
                    if (k16 >= K0) {
                        unsigned bin = (k16 - K0) >> 4; if (bin > 127u) bin = 127u;
                        atomicAdd(&hpack[(ch - 1) * (NBIN / 4) + (bin >> 2)],
                                  1u << (8 * (bin & 3)));
                    }
                }
                if (++ch == C_N) { ch = 0; ++r; }
            }
        }
        __syncthreads();
        for (int i = tid; i < NCLS * 8; i += NTHR) {
            int row = i >> 3, j = i & 7;
            const unsigned* t32 = (const unsigned*)&tile[row][8 * j];
            uint4 w;
            w.x = t32[0]; w.y = t32[1]; w.z = t32[2]; w.w = t32[3];
            *(uint4*)(keys + ((size_t)(b * NCLS + row)) * A_PAD + a0 + 8 * j) = w;
        }
    } else {
        const int total = an * C_N;
        for (int i = tid; i < total; i += NTHR) {
            int r = i / C_N, ch = i - r * C_N;
            float x = src[i];
            if (ch > 0) {
                unsigned k16 = ((double)x > THR_LOGIT) ? (mapf(x) >> 16) : 0u;
                tile[ch - 1][r] = (unsigned short)k16;
                if (k16 >= K0) {
                    unsigned bin = (k16 - K0) >> 4; if (bin > 127u) bin = 127u;
                    atomicAdd(&hpack[(ch - 1) * (NBIN / 4) + (bin >> 2)],
                              1u << (8 * (bin & 3)));
                }
            }
        }
        __syncthreads();
        for (int i = tid; i < NCLS * TA; i += NTHR) {
            int row = i / TA, col = i - row * TA;
            int a = a0 + col;
            if (a < A_PAD)
                keys[((size_t)(b * NCLS + row)) * A_PAD + a] =
                    (col < an) ? tile[row][col] : (unsigned short)0;
        }
    }

    // flush per-class mini-hist to global (L2-resident, sparse)
    unsigned* grow = ghist + (size_t)(b * NCLS) * NBIN;
    for (int i = tid; i < NCLS * (NBIN / 4); i += NTHR) {
        unsigned v = hpack[i];
        if (v) {
            int cls = i >> 5;           // / (NBIN/4)=32
            int b4  = i & 31;
            #pragma unroll
            for (int l = 0; l < 4; ++l) {
                unsigned cnt = (v >> (8 * l)) & 0xFFu;
                if (cnt) atomicAdd(&grow[cls * NBIN + 4 * b4 + l], cnt);
            }
        }
    }
}

// ---- Kernel M: one task per block (hist precomputed; f32 decode; lazy f64) ----
__global__ __launch_bounds__(NTHR) void ssd_nms_kernel(
    const float* __restrict__ logits,
    const unsigned short* __restrict__ keys,
    const unsigned* __restrict__ ghist,
    const float* __restrict__ boxreg,
    const float* __restrict__ priors,
    float* __restrict__ out)
{
    const int task = blockIdx.x;
    const int b = task / NCLS;
    const int c = task % NCLS;
    const int tid = threadIdx.x;

    __shared__ unsigned candi[CAND];
    __shared__ unsigned long long cand[CAND];
    __shared__ unsigned long long ssel[TOPK];
    __shared__ float fb0[TOPK], fb1[TOPK], fb2[TOPK], fb3[TOPK];
    __shared__ float farea[TOPK], fscore[TOPK];
    __shared__ float4 rbox[TOPK], pbox[TOPK];
    __shared__ int svalid[TOPK];
    __shared__ unsigned long long supmask[TOPK][2];
    __shared__ unsigned long long keepw[2];
    __shared__ unsigned wtot[2];
    __shared__ int scal[2];

    const float* lg = logits + ((size_t)b * A_N * C_N) + (c + 1);

    for (int i = tid; i < CAND; i += NTHR) cand[i] = 0ull;
    if (tid < TOPK) ssel[tid] = 0ull;
    if (tid == 0) { scal[0] = 0; scal[1] = 1; }
    __syncthreads();

    // ---- cutoff from precomputed 128-bin hist row (2-wave suffix scan)
    {
        unsigned h = 0;
        if (tid < NBIN) h = ghist[(size_t)task * NBIN + tid];
        unsigned incl = h;
        int lane = tid & 63;
        #pragma unroll
        for (int off = 1; off < 64; off <<= 1) {
            unsigned v = __shfl_down(incl, off);
            if (lane + off < 64) incl += v;
        }
        if (tid < NBIN && lane == 0) wtot[tid >> 6] = incl;
        __syncthreads();
        if (tid < NBIN) {
            unsigned S = incl + ((tid < 64) ? wtot[1] : 0u);
            if (S >= TOPK && (S - h) < TOPK)
                scal[1] = (int)(K0 + ((unsigned)tid << 4));
        }
        __syncthreads();
    }
    const unsigned cut16 = (unsigned)scal[1];

    // ---- single gather pass over u16 keys
    {
        const uint4* ksrc = (const uint4*)(keys + (size_t)task * A_PAD);
        #pragma unroll
        for (int j = 0; j < KPT16; ++j) {
            int i = tid + j * NTHR;
            if (i < NV4K) {
                uint4 v = ksrc[i];
                int a8 = 8 * i;
                unsigned k; int p;
                k = v.x & 0xFFFFu; if (k >= cut16) { p = atomicAdd(&scal[0],1); if (p<CAND) candi[p] = a8+0; }
                k = v.x >> 16;     if (k >= cut16) { p = atomicAdd(&scal[0],1); if (p<CAND) candi[p] = a8+1; }
                k = v.y & 0xFFFFu; if (k >= cut16) { p = atomicAdd(&scal[0],1); if (p<CAND) candi[p] = a8+2; }
                k = v.y >> 16;     if (k >= cut16) { p = atomicAdd(&scal[0],1); if (p<CAND) candi[p] = a8+3; }
                k = v.z & 0xFFFFu; if (k >= cut16) { p = atomicAdd(&scal[0],1); if (p<CAND) candi[p] = a8+4; }
                k = v.z >> 16;     if (k >= cut16) { p = atomicAdd(&scal[0],1); if (p<CAND) candi[p] = a8+5; }
                k = v.w & 0xFFFFu; if (k >= cut16) { p = atomicAdd(&scal[0],1); if (p<CAND) candi[p] = a8+6; }
                k = v.w >> 16;     if (k >= cut16) { p = atomicAdd(&scal[0],1); if (p<CAND) candi[p] = a8+7; }
            }
        }
    }
    __syncthreads();
    const int M = min(scal[0], CAND);

    // ---- rebuild full-precision keys for the ~M candidates (L3 hits)
    for (int i = tid; i < M; i += NTHR) {
        unsigned a = candi[i];
        float x = lg[(size_t)a * C_N];
        cand[i] = ((unsigned long long)mapf(x) << 32) | (unsigned)(~a);
    }
    __syncthreads();

    // ---- exact rank via all-pairs (order-independent, broadcast reads)
    {
        int Mr = (M + 7) & ~7;
        for (int i = tid; i < Mr; i += NTHR) {
            unsigned long long mykey = cand[i];
            int rank = 0;
            #pragma unroll 8
            for (int j = 0; j < Mr; ++j) rank += (cand[j] > mykey) ? 1 : 0;
            if (mykey != 0ull && rank < TOPK) ssel[rank] = mykey;
        }
    }
    __syncthreads();

    // ---- decode top-100 in f32 (hw exp); stash raw r4/p4 for lazy f64 recheck
    if (tid < TOPK) {
        unsigned long long key = ssel[tid];
        int valid = (key != 0ull);
        float b0 = 0, b1 = 0, b2 = 0, b3 = 0, area = 0, sc = 0;
        float4 r4 = make_float4(0.f, 0.f, 0.f, 0.f), p4 = r4;
        if (valid) {
            int a = (int)(~(unsigned)key);
            float x = unmapf((unsigned)(key >> 32));
            sc = 1.0f / (1.0f + __expf(-x));
            r4 = *(const float4*)(boxreg + ((size_t)b * A_N + a) * 4);
            p4 = *(const float4*)(priors + (size_t)a * 4);
            float ty = r4.x * 0.1f, tx = r4.y * 0.1f;
            float th = r4.z * 0.2f, tw = r4.w * 0.2f;
            float cy = ty * p4.z + p4.x;
            float cx = tx * p4.w + p4.y;
            float hh = __expf(th) * p4.z;
            float ww = __expf(tw) * p4.w;
            b0 = cy - hh * 0.5f; b1 = cx - ww * 0.5f;
            b2 = cy + hh * 0.5f; b3 = cx + ww * 0.5f;
            area = fmaxf(b2 - b0, 0.f) * fmaxf(b3 - b1, 0.f);
        }
        fb0[tid] = b0; fb1[tid] = b1; fb2[tid] = b2; fb3[tid] = b3;
        farea[tid] = area; fscore[tid] = sc;
        rbox[tid] = r4; pbox[tid] = p4;
        svalid[tid] = valid;
    }
    __syncthreads();

    // ---- suppression bitmask: f32 screen, exact-f64 recheck in ambiguous window
    if (tid < 2 * TOPK) {
        int i = tid >> 1, w = tid & 1;
        unsigned long long m = 0;
        if (svalid[i]) {
            float i0 = fb0[i], i1 = fb1[i], i2 = fb2[i], i3 = fb3[i], ia = farea[i];
            int jbase = w * 64;
            int jend = min(jbase + 64, TOPK);
            int jstart = (jbase > i + 1) ? jbase : (i + 1);
            for (int j = jstart; j < jend; ++j) {
                float tl0 = fmaxf(i0, fb0[j]);
                float tl1 = fmaxf(i1, fb1[j]);
                float br0 = fminf(i2, fb2[j]);
                float br1 = fminf(i3, fb3[j]);
                float wh0 = fmaxf(br0 - tl0, 0.0f);
                float wh1 = fmaxf(br1 - tl1, 0.0f);
                float inter = wh0 * wh1;
                float denom = (ia + farea[j]) - inter;
                bool sup = inter > 0.601f * denom;
                bool amb = !sup && (inter > 0.599f * denom) && (inter > 0.0f);
                if (__any(amb)) {
                    if (amb) {
                        double bi[4], bj[4], ai, aj;
                        dec64(rbox[i], pbox[i], bi, &ai);
                        dec64(rbox[j], pbox[j], bj, &aj);
                        double tl0d = fmax(bi[0], bj[0]);
                        double tl1d = fmax(bi[1], bj[1]);
                        double br0d = fmin(bi[2], bj[2]);
                        double br1d = fmin(bi[3], bj[3]);
                        double wh0d = br0d - tl0d; if (wh0d < 0.0) wh0d = 0.0;
                        double wh1d = br1d - tl1d; if (wh1d < 0.0) wh1d = 0.0;
                        double interd = wh0d * wh1d;
                        double denomd = ((ai + aj) - interd) + 1e-9;
                        sup = interd > 0.6 * denomd;
                    }
                }
                if (sup) m |= 1ull << (j - jbase);
            }
        }
        supmask[i][w] = m;
    }
    __syncthreads();

    // ---- serial greedy scan over bitmasks
    if (tid == 0) {
        unsigned long long kp0 = ~0ull, kp1 = ~0ull;
        for (int i = 0; i < TOPK; ++i) {
            bool kb = (i < 64) ? ((kp0 >> i) & 1ull) : ((kp1 >> (i - 64)) & 1ull);
            if (kb && svalid[i]) { kp0 &= ~supmask[i][0]; kp1 &= ~supmask[i][1]; }
        }
        keepw[0] = kp0; keepw[1] = kp1;
    }
    __syncthreads();

    // ---- write 5 floats per slot
    if (tid < TOPK) {
        bool kb = (tid < 64) ? ((keepw[0] >> tid) & 1ull)
                             : ((keepw[1] >> (tid - 64)) & 1ull);
        bool kp = kb && (svalid[tid] != 0);
        size_t base = ((size_t)task * TOPK + tid) * 5;
        out[base + 0] = kp ? fb0[tid] : 0.0f;
        out[base + 1] = kp ? fb1[tid] : 0.0f;
        out[base + 2] = kp ? fb2[tid] : 0.0f;
        out[base + 3] = kp ? fb3[tid] : 0.0f;
        out[base + 4] = kp ? fscore[tid] : 0.0f;
    }
}

// ---- Fallback (ws too small): strided reads, in-kernel 2048-bin hist (R7 path)
__global__ __launch_bounds__(NTHR) void ssd_nms_fallback(
    const float* __restrict__ logits,
    const float* __restrict__ boxreg,
    const float* __restrict__ priors,
    float* __restrict__ out)
{
    const int task = blockIdx.x;
    const int b = task / NCLS;
    const int c = task % NCLS;
    const int tid = threadIdx.x;

    __shared__ unsigned hist[2048];
    __shared__ unsigned wt4[4];
    __shared__ unsigned candi[CAND];
    __shared__ unsigned long long cand[CAND];
    __shared__ unsigned long long ssel[TOPK];
    __shared__ float fb0[TOPK], fb1[TOPK], fb2[TOPK], fb3[TOPK];
    __shared__ float farea[TOPK], fscore[TOPK];
    __shared__ float4 rbox[TOPK], pbox[TOPK];
    __shared__ int svalid[TOPK];
    __shared__ unsigned long long supmask[TOPK][2];
    __shared__ unsigned long long keepw[2];
    __shared__ int scal[2];

    const float* lg = logits + ((size_t)b * A_N * C_N) + (c + 1);

    for (int k = tid; k < 2048; k += NTHR) hist[k] = 0;
    for (int i = tid; i < CAND; i += NTHR) cand[i] = 0ull;
    if (tid < TOPK) ssel[tid] = 0ull;
    if (tid == 0) { scal[0] = 0; scal[1] = 1; }
    __syncthreads();

    for (int a = tid; a < A_N; a += NTHR) {
        float x = lg[(size_t)a * C_N];
        if ((double)x > THR_LOGIT) atomicAdd(&hist[mapf(x) >> 21], 1u);
    }
    __syncthreads();
    {
        unsigned s = 0;
        #pragma unroll
        for (int k = 0; k < 8; ++k) s += hist[tid * 8 + k];
        unsigned incl = s;
        int lane = tid & 63;
        #pragma unroll
        for (int off = 1; off < 64; off <<= 1) {
            unsigned v = __shfl_down(incl, off);
            if (lane + off < 64) incl += v;
        }
        if (lane == 0) wt4[tid >> 6] = incl;
        __syncthreads();
        unsigned hi = 0;
        #pragma unroll
        for (int w = 0; w < 4; ++w) if (w > (tid >> 6)) hi += wt4[w];
        unsigned excl = hi + (incl - s);
        if (excl < TOPK && excl + s >= TOPK) {
            unsigned running = excl;
            #pragma unroll
            for (int k = 7; k >= 0; --k) {
                running += hist[tid * 8 + k];
                if (running >= TOPK) { scal[1] = (int)(((unsigned)(tid * 8 + k)) << 21); break; }
            }
        }
    }
    __syncthreads();
    const unsigned cutoff = (unsigned)scal[1];

    for (int a = tid; a < A_N; a += NTHR) {
        float x = lg[(size_t)a * C_N];
        if ((double)x > THR_LOGIT) {
            unsigned u = mapf(x);
            if (u >= cutoff) {
                int p = atomicAdd(&scal[0], 1);
                if (p < CAND) { candi[p] = (unsigned)a; cand[p] = ((unsigned long long)u << 32) | (unsigned)(~(unsigned)a); }
            }
        }
    }
    __syncthreads();
    const int M = min(scal[0], CAND);
    {
        int Mr = (M + 7) & ~7;
        for (int i = tid; i < Mr; i += NTHR) {
            unsigned long long mykey = cand[i];
            int rank = 0;
            for (int j = 0; j < Mr; ++j) rank += (cand[j] > mykey) ? 1 : 0;
            if (mykey != 0ull && rank < TOPK) ssel[rank] = mykey;
        }
    }
    __syncthreads();
    if (tid < TOPK) {
        unsigned long long key = ssel[tid];
        int valid = (key != 0ull);
        float b0 = 0, b1 = 0, b2 = 0, b3 = 0, area = 0, sc = 0;
        float4 r4 = make_float4(0.f,0.f,0.f,0.f), p4 = r4;
        if (valid) {
            int a = (int)(~(unsigned)key);
            float x = unmapf((unsigned)(key >> 32));
            sc = 1.0f / (1.0f + __expf(-x));
            r4 = *(const float4*)(boxreg + ((size_t)b * A_N + a) * 4);
            p4 = *(const float4*)(priors + (size_t)a * 4);
            float cy = r4.x * 0.1f * p4.z + p4.x;
            float cx = r4.y * 0.1f * p4.w + p4.y;
            float hh = __expf(r4.z * 0.2f) * p4.z;
            float ww = __expf(r4.w * 0.2f) * p4.w;
            b0 = cy - hh * 0.5f; b1 = cx - ww * 0.5f;
            b2 = cy + hh * 0.5f; b3 = cx + ww * 0.5f;
            area = fmaxf(b2 - b0, 0.f) * fmaxf(b3 - b1, 0.f);
        }
        fb0[tid]=b0; fb1[tid]=b1; fb2[tid]=b2; fb3[tid]=b3;
        farea[tid]=area; fscore[tid]=sc; rbox[tid]=r4; pbox[tid]=p4; svalid[tid]=valid;
    }
    __syncthreads();
    if (tid < 2 * TOPK) {
        int i = tid >> 1, w = tid & 1;
        unsigned long long m = 0;
        if (svalid[i]) {
            float i0=fb0[i], i1=fb1[i], i2=fb2[i], i3=fb3[i], ia=farea[i];
            int jbase = w * 64, jend = min(jbase + 64, TOPK);
            int jstart = (jbase > i + 1) ? jbase : (i + 1);
            for (int j = jstart; j < jend; ++j) {
                float tl0=fmaxf(i0,fb0[j]), tl1=fmaxf(i1,fb1[j]);
                float br0=fminf(i2,fb2[j]), br1=fminf(i3,fb3[j]);
                float wh0=fmaxf(br0-tl0,0.f), wh1=fmaxf(br1-tl1,0.f);
                float inter=wh0*wh1, denom=(ia+farea[j])-inter;
                bool sup = inter > 0.601f*denom;
                bool amb = !sup && (inter > 0.599f*denom) && (inter > 0.f);
                if (__any(amb)) {
                    if (amb) {
                        double bi[4], bj[4], ai, aj;
                        dec64(rbox[i], pbox[i], bi, &ai);
                        dec64(rbox[j], pbox[j], bj, &aj);
                        double wh0d = fmin(bi[2],bj[2]) - fmax(bi[0],bj[0]); if (wh0d<0) wh0d=0;
                        double wh1d = fmin(bi[3],bj[3]) - fmax(bi[1],bj[1]); if (wh1d<0) wh1d=0;
                        double interd = wh0d*wh1d;
                        sup = interd > 0.6 * (((ai+aj)-interd)+1e-9);
                    }
                }
                if (sup) m |= 1ull << (j - jbase);
            }
        }
        supmask[i][w] = m;
    }
    __syncthreads();
    if (tid == 0) {
        unsigned long long kp0 = ~0ull, kp1 = ~0ull;
        for (int i = 0; i < TOPK; ++i) {
            bool kb = (i < 64) ? ((kp0 >> i) & 1ull) : ((kp1 >> (i - 64)) & 1ull);
            if (kb && svalid[i]) { kp0 &= ~supmask[i][0]; kp1 &= ~supmask[i][1]; }
        }
        keepw[0] = kp0; keepw[1] = kp1;
    }
    __syncthreads();
    if (tid < TOPK) {
        bool kb = (tid < 64) ? ((keepw[0] >> tid) & 1ull)
                             : ((keepw[1] >> (tid - 64)) & 1ull);
        bool kp = kb && (svalid[tid] != 0);
        size_t base = ((size_t)task * TOPK + tid) * 5;
        out[base + 0] = kp ? fb0[tid] : 0.0f;
        out[base + 1] = kp ? fb1[tid] : 0.0f;
        out[base + 2] = kp ? fb2[tid] : 0.0f;
        out[base + 3] = kp ? fb3[tid] : 0.0f;
        out[base + 4] = kp ? fscore[tid] : 0.0f;
    }
}

extern "C" void kernel_launch(void* const* d_in, const int* in_sizes, int n_in,
                              void* d_out, int out_size, void* d_ws, size_t ws_size,
                              hipStream_t stream) {
    const float* logits = (const float*)d_in[0];
    const float* boxreg = (const float*)d_in[1];
    const float* priors = (const float*)d_in[2];
    float* out = (float*)d_out;

    const size_t keys_bytes = (size_t)NTASK * A_PAD * sizeof(unsigned short); // 44.73 MB
    const size_t hist_bytes = (size_t)NTASK * NBIN * sizeof(unsigned);        // 1.31 MB
    if (ws_size >= keys_bytes + hist_bytes) {
        unsigned short* keysw = (unsigned short*)d_ws;
        unsigned* ghist = (unsigned*)((char*)d_ws + keys_bytes);
        hipMemsetAsync(ghist, 0, hist_bytes, stream);
        const int NT = (A_N + TA - 1) / TA;
        key_transpose_kernel<<<dim3(B_N * NT), dim3(NTHR), 0, stream>>>(logits, keysw, ghist);
        ssd_nms_kernel<<<dim3(NTASK), dim3(NTHR), 0, stream>>>(
            logits, keysw, ghist, boxreg, priors, out);
    } else {
        ssd_nms_fallback<<<dim3(NTASK), dim3(NTHR), 0, stream>>>(
            logits, boxreg, priors, out);
    }
}

// Round 9
// 97.949 us; speedup vs baseline: 2.2707x; 2.2707x over previous
//
#include <hip/hip_runtime.h>
#include <math.h>

#define A_N   8732
#define A_PAD 8736            // A_N rounded up to 8 (u16 pad, zeros)
#define C_N   81
#define B_N   32
#define NCLS  80
#define NTASK (B_N * NCLS)
#define TOPK  100
#define NTHR  256
#define CAND  512
#define TA    64
#define NV4K  (A_PAD / 8)     // 1092 uint4 (8 u16 keys each) per key row
#define KPT16 5               // ceil(NV4K / NTHR)
#define K0    0xBE00u         // k16 >= K0  <=>  x >= 0.125
#define NBIN  128             // fine bins of 16 u16-steps over [K0, K0+2048)

// ln(3/7) in f64: sigmoid_f64(x) > 0.3  <=>  x > THR_LOGIT
#define THR_LOGIT (-0.8472978603872034)

// Monotone map: float bits -> unsigned, order-preserving. 0 = invalid sentinel.
__device__ __forceinline__ unsigned mapf(float x) {
    unsigned b = __float_as_uint(x);
    return b ^ ((b & 0x80000000u) ? 0xFFFFFFFFu : 0x80000000u);
}
__device__ __forceinline__ float unmapf(unsigned u) {
    unsigned b = (u & 0x80000000u) ? (u ^ 0x80000000u) : ~u;
    return __uint_as_float(b);
}

// Exact f64 decode (reference op order) from raw regression/prior values.
__device__ __forceinline__ void dec64(const float4 r4, const float4 p4,
                                      double* bx, double* area) {
    double ty = (double)r4.x / 10.0, tx = (double)r4.y / 10.0;
    double th = (double)r4.z / 5.0,  tw = (double)r4.w / 5.0;
    double cy = ty * (double)p4.z + (double)p4.x;
    double cx = tx * (double)p4.w + (double)p4.y;
    double hh = exp(th) * (double)p4.z;
    double ww = exp(tw) * (double)p4.w;
    bx[0] = cy - hh / 2.0; bx[1] = cx - ww / 2.0;
    bx[2] = cy + hh / 2.0; bx[3] = cx + ww / 2.0;
    double e0 = bx[2] - bx[0]; if (e0 < 0.0) e0 = 0.0;
    double e1 = bx[3] - bx[1]; if (e1 < 0.0) e1 = 0.0;
    *area = e0 * e1;
}

// ---- Kernel T: coalesced logits read, u16 keys transposed to (B, 80, A_PAD) ----
// (R7 version: pure transpose, no histogram — BW-roofline ~21 us)
__global__ __launch_bounds__(NTHR) void key_transpose_kernel(
    const float* __restrict__ logits,          // (B, A, 81)
    unsigned short* __restrict__ keys)         // (B, 80, A_PAD) u16
{
    __shared__ unsigned short tile[NCLS][TA + 2];   // 80 x 66 u16 = 10.3 KB
    const int NT = (A_N + TA - 1) / TA;             // 137
    const int b  = blockIdx.x / NT;
    const int t0 = blockIdx.x % NT;
    const int a0 = t0 * TA;
    const int an = min(TA, A_N - a0);
    const int tid = threadIdx.x;

    const float* src = logits + ((size_t)b * A_N + a0) * C_N;

    if (an == TA) {
        const float4* src4 = (const float4*)src;
        const int total4 = TA * C_N / 4;            // 1296
        for (int i = tid; i < total4; i += NTHR) {
            float4 v = src4[i];
            int base = 4 * i;
            int r  = base / C_N;
            int ch = base - r * C_N;
            float xs[4] = { v.x, v.y, v.z, v.w };
            #pragma unroll
            for (int k = 0; k < 4; ++k) {
                if (ch > 0)
                    tile[ch - 1][r] = (unsigned short)
                        (((double)xs[k] > THR_LOGIT) ? (mapf(xs[k]) >> 16) : 0u);
                if (++ch == C_N) { ch = 0; ++r; }
            }
        }
        __syncthreads();
        for (int i = tid; i < NCLS * 8; i += NTHR) {
            int row = i >> 3, j = i & 7;
            const unsigned* t32 = (const unsigned*)&tile[row][8 * j];
            uint4 w;
            w.x = t32[0]; w.y = t32[1]; w.z = t32[2]; w.w = t32[3];
            *(uint4*)(keys + ((size_t)(b * NCLS + row)) * A_PAD + a0 + 8 * j) = w;
        }
    } else {
        const int total = an * C_N;
        for (int i = tid; i < total; i += NTHR) {
            int r = i / C_N, ch = i - r * C_N;
            float x = src[i];
            if (ch > 0)
                tile[ch - 1][r] = (unsigned short)
                    (((double)x > THR_LOGIT) ? (mapf(x) >> 16) : 0u);
        }
        __syncthreads();
        for (int i = tid; i < NCLS * TA; i += NTHR) {
            int row = i / TA, col = i - row * TA;
            int a = a0 + col;
            if (a < A_PAD)
                keys[((size_t)(b * NCLS + row)) * A_PAD + a] =
                    (col < an) ? tile[row][col] : (unsigned short)0;
        }
    }
}

// histogram helper: count one u16 key into the fine hist (k >= K0 only)
__device__ __forceinline__ void hcount(unsigned k, unsigned* hist) {
    if (k >= K0) {
        unsigned bin = (k - K0) >> 4; if (bin > (NBIN - 1)) bin = NBIN - 1;
        atomicAdd(&hist[bin], 1u);
    }
}

// ---- Kernel M: one task per block; reg-staged u16 keys; 128-bin hist; f32 decode
__global__ __launch_bounds__(NTHR) void ssd_nms_kernel(
    const float* __restrict__ logits,
    const unsigned short* __restrict__ keys,
    const float* __restrict__ boxreg,
    const float* __restrict__ priors,
    float* __restrict__ out)
{
    const int task = blockIdx.x;
    const int b = task / NCLS;
    const int c = task % NCLS;
    const int tid = threadIdx.x;

    __shared__ unsigned hist[NBIN];
    __shared__ unsigned candi[CAND];
    __shared__ unsigned long long cand[CAND];
    __shared__ unsigned long long ssel[TOPK];
    __shared__ float fb0[TOPK], fb1[TOPK], fb2[TOPK], fb3[TOPK];
    __shared__ float farea[TOPK], fscore[TOPK];
    __shared__ float4 rbox[TOPK], pbox[TOPK];
    __shared__ int svalid[TOPK];
    __shared__ unsigned long long supmask[TOPK][2];
    __shared__ unsigned long long keepw[2];
    __shared__ unsigned wtot[2];
    __shared__ int scal[2];

    const float* lg = logits + ((size_t)b * A_N * C_N) + (c + 1);

    // ---- stage the task's u16 key row into registers (5 uint4/thread)
    uint4 kreg[KPT16];
    {
        const uint4* ksrc = (const uint4*)(keys + (size_t)task * A_PAD);
        #pragma unroll
        for (int j = 0; j < KPT16; ++j) {
            int i = tid + j * NTHR;
            kreg[j] = (i < NV4K) ? ksrc[i] : make_uint4(0u, 0u, 0u, 0u);
        }
    }

    if (tid < NBIN) hist[tid] = 0;
    for (int i = tid; i < CAND; i += NTHR) cand[i] = 0ull;
    if (tid < TOPK) ssel[tid] = 0ull;
    if (tid == 0) { scal[0] = 0; scal[1] = 1; }
    __syncthreads();

    // ---- Pass A: fine 128-bin histogram of keys >= K0 (from registers)
    #pragma unroll
    for (int j = 0; j < KPT16; ++j) {
        uint4 v = kreg[j];
        hcount(v.x & 0xFFFFu, hist); hcount(v.x >> 16, hist);
        hcount(v.y & 0xFFFFu, hist); hcount(v.y >> 16, hist);
        hcount(v.z & 0xFFFFu, hist); hcount(v.z >> 16, hist);
        hcount(v.w & 0xFFFFu, hist); hcount(v.w >> 16, hist);
    }
    __syncthreads();

    // ---- cutoff via 2-wave suffix scan over 128 bins
    {
        unsigned h = (tid < NBIN) ? hist[tid] : 0u;
        unsigned incl = h;
        int lane = tid & 63;
        #pragma unroll
        for (int off = 1; off < 64; off <<= 1) {
            unsigned v = __shfl_down(incl, off);
            if (lane + off < 64) incl += v;
        }
        if (tid < NBIN && lane == 0) wtot[tid >> 6] = incl;
        __syncthreads();
        if (tid < NBIN) {
            unsigned S = incl + ((tid < 64) ? wtot[1] : 0u);   // suffix sum bins tid..127
            if (S >= TOPK && (S - h) < TOPK)
                scal[1] = (int)(K0 + ((unsigned)tid << 4));
        }
        __syncthreads();

        // rare fallback: fewer than TOPK keys above K0 -> coarse bins over [0x4000,K0)
        unsigned T = wtot[0] + wtot[1];
        if (T < TOPK) {
            if (tid < NBIN) hist[tid] = 0;
            __syncthreads();
            #pragma unroll
            for (int j = 0; j < KPT16; ++j) {
                uint4 v = kreg[j];
                unsigned k;
                k = v.x & 0xFFFFu; if (k >= 0x4000u && k < K0) atomicAdd(&hist[(k - 0x4000u) >> 8], 1u);
                k = v.x >> 16;     if (k >= 0x4000u && k < K0) atomicAdd(&hist[(k - 0x4000u) >> 8], 1u);
                k = v.y & 0xFFFFu; if (k >= 0x4000u && k < K0) atomicAdd(&hist[(k - 0x4000u) >> 8], 1u);
                k = v.y >> 16;     if (k >= 0x4000u && k < K0) atomicAdd(&hist[(k - 0x4000u) >> 8], 1u);
                k = v.z & 0xFFFFu; if (k >= 0x4000u && k < K0) atomicAdd(&hist[(k - 0x4000u) >> 8], 1u);
                k = v.z >> 16;     if (k >= 0x4000u && k < K0) atomicAdd(&hist[(k - 0x4000u) >> 8], 1u);
                k = v.w & 0xFFFFu; if (k >= 0x4000u && k < K0) atomicAdd(&hist[(k - 0x4000u) >> 8], 1u);
                k = v.w >> 16;     if (k >= 0x4000u && k < K0) atomicAdd(&hist[(k - 0x4000u) >> 8], 1u);
            }
            __syncthreads();
            unsigned h2 = (tid < NBIN) ? hist[tid] : 0u;
            unsigned incl2 = h2;
            #pragma unroll
            for (int off = 1; off < 64; off <<= 1) {
                unsigned v = __shfl_down(incl2, off);
                if (lane + off < 64) incl2 += v;
            }
            if (tid < NBIN && lane == 0) wtot[tid >> 6] = incl2;
            __syncthreads();
            if (tid < NBIN) {
                unsigned S2 = incl2 + ((tid < 64) ? wtot[1] : 0u);
                unsigned need = TOPK - T;
                if (S2 >= need && (S2 - h2) < need)
                    scal[1] = (int)(0x4000u + ((unsigned)tid << 8));
            }
            __syncthreads();
        }
    }
    const unsigned cut16 = (unsigned)scal[1];

    // ---- Pass B1: gather candidate indices (k16 >= cut16); padded keys are 0
    #pragma unroll
    for (int j = 0; j < KPT16; ++j) {
        uint4 v = kreg[j];
        int a8 = 8 * (tid + j * NTHR);
        unsigned k; int p;
        k = v.x & 0xFFFFu; if (k >= cut16) { p = atomicAdd(&scal[0],1); if (p<CAND) candi[p] = a8+0; }
        k = v.x >> 16;     if (k >= cut16) { p = atomicAdd(&scal[0],1); if (p<CAND) candi[p] = a8+1; }
        k = v.y & 0xFFFFu; if (k >= cut16) { p = atomicAdd(&scal[0],1); if (p<CAND) candi[p] = a8+2; }
        k = v.y >> 16;     if (k >= cut16) { p = atomicAdd(&scal[0],1); if (p<CAND) candi[p] = a8+3; }
        k = v.z & 0xFFFFu; if (k >= cut16) { p = atomicAdd(&scal[0],1); if (p<CAND) candi[p] = a8+4; }
        k = v.z >> 16;     if (k >= cut16) { p = atomicAdd(&scal[0],1); if (p<CAND) candi[p] = a8+5; }
        k = v.w & 0xFFFFu; if (k >= cut16) { p = atomicAdd(&scal[0],1); if (p<CAND) candi[p] = a8+6; }
        k = v.w >> 16;     if (k >= cut16) { p = atomicAdd(&scal[0],1); if (p<CAND) candi[p] = a8+7; }
    }
    __syncthreads();
    const int M = min(scal[0], CAND);

    // ---- Pass B2: rebuild full-precision keys for the ~M candidates (L2/L3 hits)
    for (int i = tid; i < M; i += NTHR) {
        unsigned a = candi[i];
        float x = lg[(size_t)a * C_N];
        cand[i] = ((unsigned long long)mapf(x) << 32) | (unsigned)(~a);
    }
    __syncthreads();

    // ---- exact rank via all-pairs (order-independent, broadcast reads)
    {
        int Mr = (M + 7) & ~7;
        for (int i = tid; i < Mr; i += NTHR) {
            unsigned long long mykey = cand[i];
            int rank = 0;
            #pragma unroll 8
            for (int j = 0; j < Mr; ++j) rank += (cand[j] > mykey) ? 1 : 0;
            if (mykey != 0ull && rank < TOPK) ssel[rank] = mykey;
        }
    }
    __syncthreads();

    // ---- decode top-100 in f32 (hw exp); stash raw r4/p4 for lazy f64 recheck
    if (tid < TOPK) {
        unsigned long long key = ssel[tid];
        int valid = (key != 0ull);
        float b0 = 0, b1 = 0, b2 = 0, b3 = 0, area = 0, sc = 0;
        float4 r4 = make_float4(0.f, 0.f, 0.f, 0.f), p4 = r4;
        if (valid) {
            int a = (int)(~(unsigned)key);
            float x = unmapf((unsigned)(key >> 32));
            sc = 1.0f / (1.0f + __expf(-x));
            r4 = *(const float4*)(boxreg + ((size_t)b * A_N + a) * 4);
            p4 = *(const float4*)(priors + (size_t)a * 4);
            float ty = r4.x * 0.1f, tx = r4.y * 0.1f;
            float th = r4.z * 0.2f, tw = r4.w * 0.2f;
            float cy = ty * p4.z + p4.x;
            float cx = tx * p4.w + p4.y;
            float hh = __expf(th) * p4.z;
            float ww = __expf(tw) * p4.w;
            b0 = cy - hh * 0.5f; b1 = cx - ww * 0.5f;
            b2 = cy + hh * 0.5f; b3 = cx + ww * 0.5f;
            area = fmaxf(b2 - b0, 0.f) * fmaxf(b3 - b1, 0.f);
        }
        fb0[tid] = b0; fb1[tid] = b1; fb2[tid] = b2; fb3[tid] = b3;
        farea[tid] = area; fscore[tid] = sc;
        rbox[tid] = r4; pbox[tid] = p4;
        svalid[tid] = valid;
    }
    __syncthreads();

    // ---- suppression bitmask: f32 screen, exact-f64 recheck in ambiguous window
    if (tid < 2 * TOPK) {
        int i = tid >> 1, w = tid & 1;
        unsigned long long m = 0;
        if (svalid[i]) {
            float i0 = fb0[i], i1 = fb1[i], i2 = fb2[i], i3 = fb3[i], ia = farea[i];
            int jbase = w * 64;
            int jend = min(jbase + 64, TOPK);
            int jstart = (jbase > i + 1) ? jbase : (i + 1);
            for (int j = jstart; j < jend; ++j) {
                float tl0 = fmaxf(i0, fb0[j]);
                float tl1 = fmaxf(i1, fb1[j]);
                float br0 = fminf(i2, fb2[j]);
                float br1 = fminf(i3, fb3[j]);
                float wh0 = fmaxf(br0 - tl0, 0.0f);
                float wh1 = fmaxf(br1 - tl1, 0.0f);
                float inter = wh0 * wh1;
                float denom = (ia + farea[j]) - inter;
                bool sup = inter > 0.601f * denom;
                bool amb = !sup && (inter > 0.599f * denom) && (inter > 0.0f);
                if (__any(amb)) {
                    if (amb) {
                        double bi[4], bj[4], ai, aj;
                        dec64(rbox[i], pbox[i], bi, &ai);
                        dec64(rbox[j], pbox[j], bj, &aj);
                        double tl0d = fmax(bi[0], bj[0]);
                        double tl1d = fmax(bi[1], bj[1]);
                        double br0d = fmin(bi[2], bj[2]);
                        double br1d = fmin(bi[3], bj[3]);
                        double wh0d = br0d - tl0d; if (wh0d < 0.0) wh0d = 0.0;
                        double wh1d = br1d - tl1d; if (wh1d < 0.0) wh1d = 0.0;
                        double interd = wh0d * wh1d;
                        double denomd = ((ai + aj) - interd) + 1e-9;
                        sup = interd > 0.6 * denomd;
                    }
                }
                if (sup) m |= 1ull << (j - jbase);
            }
        }
        supmask[i][w] = m;
    }
    __syncthreads();

    // ---- serial greedy scan over bitmasks
    if (tid == 0) {
        unsigned long long kp0 = ~0ull, kp1 = ~0ull;
        for (int i = 0; i < TOPK; ++i) {
            bool kb = (i < 64) ? ((kp0 >> i) & 1ull) : ((kp1 >> (i - 64)) & 1ull);
            if (kb && svalid[i]) { kp0 &= ~supmask[i][0]; kp1 &= ~supmask[i][1]; }
        }
        keepw[0] = kp0; keepw[1] = kp1;
    }
    __syncthreads();

    // ---- write 5 floats per slot
    if (tid < TOPK) {
        bool kb = (tid < 64) ? ((keepw[0] >> tid) & 1ull)
                             : ((keepw[1] >> (tid - 64)) & 1ull);
        bool kp = kb && (svalid[tid] != 0);
        size_t base = ((size_t)task * TOPK + tid) * 5;
        out[base + 0] = kp ? fb0[tid] : 0.0f;
        out[base + 1] = kp ? fb1[tid] : 0.0f;
        out[base + 2] = kp ? fb2[tid] : 0.0f;
        out[base + 3] = kp ? fb3[tid] : 0.0f;
        out[base + 4] = kp ? fscore[tid] : 0.0f;
    }
}

// ---- Fallback (ws too small): strided reads, in-kernel 2048-bin hist ----
__global__ __launch_bounds__(NTHR) void ssd_nms_fallback(
    const float* __restrict__ logits,
    const float* __restrict__ boxreg,
    const float* __restrict__ priors,
    float* __restrict__ out)
{
    const int task = blockIdx.x;
    const int b = task / NCLS;
    const int c = task % NCLS;
    const int tid = threadIdx.x;

    __shared__ unsigned hist[2048];
    __shared__ unsigned wt4[4];
    __shared__ unsigned candi[CAND];
    __shared__ unsigned long long cand[CAND];
    __shared__ unsigned long long ssel[TOPK];
    __shared__ float fb0[TOPK], fb1[TOPK], fb2[TOPK], fb3[TOPK];
    __shared__ float farea[TOPK], fscore[TOPK];
    __shared__ float4 rbox[TOPK], pbox[TOPK];
    __shared__ int svalid[TOPK];
    __shared__ unsigned long long supmask[TOPK][2];
    __shared__ unsigned long long keepw[2];
    __shared__ int scal[2];

    const float* lg = logits + ((size_t)b * A_N * C_N) + (c + 1);

    for (int k = tid; k < 2048; k += NTHR) hist[k] = 0;
    for (int i = tid; i < CAND; i += NTHR) cand[i] = 0ull;
    if (tid < TOPK) ssel[tid] = 0ull;
    if (tid == 0) { scal[0] = 0; scal[1] = 1; }
    __syncthreads();

    for (int a = tid; a < A_N; a += NTHR) {
        float x = lg[(size_t)a * C_N];
        if ((double)x > THR_LOGIT) atomicAdd(&hist[mapf(x) >> 21], 1u);
    }
    __syncthreads();
    {
        unsigned s = 0;
        #pragma unroll
        for (int k = 0; k < 8; ++k) s += hist[tid * 8 + k];
        unsigned incl = s;
        int lane = tid & 63;
        #pragma unroll
        for (int off = 1; off < 64; off <<= 1) {
            unsigned v = __shfl_down(incl, off);
            if (lane + off < 64) incl += v;
        }
        if (lane == 0) wt4[tid >> 6] = incl;
        __syncthreads();
        unsigned hi = 0;
        #pragma unroll
        for (int w = 0; w < 4; ++w) if (w > (tid >> 6)) hi += wt4[w];
        unsigned excl = hi + (incl - s);
        if (excl < TOPK && excl + s >= TOPK) {
            unsigned running = excl;
            #pragma unroll
            for (int k = 7; k >= 0; --k) {
                running += hist[tid * 8 + k];
                if (running >= TOPK) { scal[1] = (int)(((unsigned)(tid * 8 + k)) << 21); break; }
            }
        }
    }
    __syncthreads();
    const unsigned cutoff = (unsigned)scal[1];

    for (int a = tid; a < A_N; a += NTHR) {
        float x = lg[(size_t)a * C_N];
        if ((double)x > THR_LOGIT) {
            unsigned u = mapf(x);
            if (u >= cutoff) {
                int p = atomicAdd(&scal[0], 1);
                if (p < CAND) { candi[p] = (unsigned)a; cand[p] = ((unsigned long long)u << 32) | (unsigned)(~(unsigned)a); }
            }
        }
    }
    __syncthreads();
    const int M = min(scal[0], CAND);
    {
        int Mr = (M + 7) & ~7;
        for (int i = tid; i < Mr; i += NTHR) {
            unsigned long long mykey = cand[i];
            int rank = 0;
            for (int j = 0; j < Mr; ++j) rank += (cand[j] > mykey) ? 1 : 0;
            if (mykey != 0ull && rank < TOPK) ssel[rank] = mykey;
        }
    }
    __syncthreads();
    if (tid < TOPK) {
        unsigned long long key = ssel[tid];
        int valid = (key != 0ull);
        float b0 = 0, b1 = 0, b2 = 0, b3 = 0, area = 0, sc = 0;
        float4 r4 = make_float4(0.f,0.f,0.f,0.f), p4 = r4;
        if (valid) {
            int a = (int)(~(unsigned)key);
            float x = unmapf((unsigned)(key >> 32));
            sc = 1.0f / (1.0f + __expf(-x));
            r4 = *(const float4*)(boxreg + ((size_t)b * A_N + a) * 4);
            p4 = *(const float4*)(priors + (size_t)a * 4);
            float cy = r4.x * 0.1f * p4.z + p4.x;
            float cx = r4.y * 0.1f * p4.w + p4.y;
            float hh = __expf(r4.z * 0.2f) * p4.z;
            float ww = __expf(r4.w * 0.2f) * p4.w;
            b0 = cy - hh * 0.5f; b1 = cx - ww * 0.5f;
            b2 = cy + hh * 0.5f; b3 = cx + ww * 0.5f;
            area = fmaxf(b2 - b0, 0.f) * fmaxf(b3 - b1, 0.f);
        }
        fb0[tid]=b0; fb1[tid]=b1; fb2[tid]=b2; fb3[tid]=b3;
        farea[tid]=area; fscore[tid]=sc; rbox[tid]=r4; pbox[tid]=p4; svalid[tid]=valid;
    }
    __syncthreads();
    if (tid < 2 * TOPK) {
        int i = tid >> 1, w = tid & 1;
        unsigned long long m = 0;
        if (svalid[i]) {
            float i0=fb0[i], i1=fb1[i], i2=fb2[i], i3=fb3[i], ia=farea[i];
            int jbase = w * 64, jend = min(jbase + 64, TOPK);
            int jstart = (jbase > i + 1) ? jbase : (i + 1);
            for (int j = jstart; j < jend; ++j) {
                float tl0=fmaxf(i0,fb0[j]), tl1=fmaxf(i1,fb1[j]);
                float br0=fminf(i2,fb2[j]), br1=fminf(i3,fb3[j]);
                float wh0=fmaxf(br0-tl0,0.f), wh1=fmaxf(br1-tl1,0.f);
                float inter=wh0*wh1, denom=(ia+farea[j])-inter;
                bool sup = inter > 0.601f*denom;
                bool amb = !sup && (inter > 0.599f*denom) && (inter > 0.f);
                if (__any(amb)) {
                    if (amb) {
                        double bi[4], bj[4], ai, aj;
                        dec64(rbox[i], pbox[i], bi, &ai);
                        dec64(rbox[j], pbox[j], bj, &aj);
                        double wh0d = fmin(bi[2],bj[2]) - fmax(bi[0],bj[0]); if (wh0d<0) wh0d=0;
                        double wh1d = fmin(bi[3],bj[3]) - fmax(bi[1],bj[1]); if (wh1d<0) wh1d=0;
                        double interd = wh0d*wh1d;
                        sup = interd > 0.6 * (((ai+aj)-interd)+1e-9);
                    }
                }
                if (sup) m |= 1ull << (j - jbase);
            }
        }
        supmask[i][w] = m;
    }
    __syncthreads();
    if (tid == 0) {
        unsigned long long kp0 = ~0ull, kp1 = ~0ull;
        for (int i = 0; i < TOPK; ++i) {
            bool kb = (i < 64) ? ((kp0 >> i) & 1ull) : ((kp1 >> (i - 64)) & 1ull);
            if (kb && svalid[i]) { kp0 &= ~supmask[i][0]; kp1 &= ~supmask[i][1]; }
        }
        keepw[0] = kp0; keepw[1] = kp1;
    }
    __syncthreads();
    if (tid < TOPK) {
        bool kb = (tid < 64) ? ((keepw[0] >> tid) & 1ull)
                             : ((keepw[1] >> (tid - 64)) & 1ull);
        bool kp = kb && (svalid[tid] != 0);
        size_t base = ((size_t)task * TOPK + tid) * 5;
        out[base + 0] = kp ? fb0[tid] : 0.0f;
        out[base + 1] = kp ? fb1[tid] : 0.0f;
        out[base + 2] = kp ? fb2[tid] : 0.0f;
        out[base + 3] = kp ? fb3[tid] : 0.0f;
        out[base + 4] = kp ? fscore[tid] : 0.0f;
    }
}

extern "C" void kernel_launch(void* const* d_in, const int* in_sizes, int n_in,
                              void* d_out, int out_size, void* d_ws, size_t ws_size,
                              hipStream_t stream) {
    const float* logits = (const float*)d_in[0];
    const float* boxreg = (const float*)d_in[1];
    const float* priors = (const float*)d_in[2];
    float* out = (float*)d_out;

    const size_t keys_bytes = (size_t)NTASK * A_PAD * sizeof(unsigned short); // 44.73 MB
    if (ws_size >= keys_bytes) {
        unsigned short* keysw = (unsigned short*)d_ws;
        const int NT = (A_N + TA - 1) / TA;
        key_transpose_kernel<<<dim3(B_N * NT), dim3(NTHR), 0, stream>>>(logits, keysw);
        ssd_nms_kernel<<<dim3(NTASK), dim3(NTHR), 0, stream>>>(
            logits, keysw, boxreg, priors, out);
    } else {
        ssd_nms_fallback<<<dim3(NTASK), dim3(NTHR), 0, stream>>>(
            logits, boxreg, priors, out);
    }
}